// Round 4
// baseline (681.753 us; speedup 1.0000x reference)
//
#include <hip/hip_runtime.h>
#include <cstdint>

// MSCN forward, round 4:
//  - k_enc v4: persistent blocks own TPB consecutive 64-row tiles with a
//    software pipeline (gathers for tile t+1 + list/splan prefetch for t+2 in
//    flight while tile t computes/reduces). Full-column carry reduce.
//  - k_head: unchanged from R3 (bf16-MFMA fused BN+MLP head).

constexpr int P_N = 20000;
constexpr int HD  = 128;

typedef __attribute__((ext_vector_type(8))) short  short8v;
typedef __attribute__((ext_vector_type(4))) float  float4v;

__device__ inline ushort f2bf(float f) {                       // RNE f32->bf16
    uint32_t u = __builtin_bit_cast(uint32_t, f);
    u += 0x7fffu + ((u >> 16) & 1u);
    return (ushort)(u >> 16);
}
__device__ inline short8v cvt8(float4 x0, float4 x1) {
    short8v v;
    v[0] = (short)f2bf(x0.x); v[1] = (short)f2bf(x0.y);
    v[2] = (short)f2bf(x0.z); v[3] = (short)f2bf(x0.w);
    v[4] = (short)f2bf(x1.x); v[5] = (short)f2bf(x1.y);
    v[6] = (short)f2bf(x1.z); v[7] = (short)f2bf(x1.w);
    return v;
}

// ---------------- histogram ----------------
__global__ void k_count(const int* __restrict__ idx, int n, int* __restrict__ counts) {
    int i = blockIdx.x * blockDim.x + threadIdx.x;
    int stride = gridDim.x * blockDim.x;
    for (; i < n; i += stride) atomicAdd(&counts[idx[i]], 1);
}

// ---------------- exclusive scan, one block per type ----------------
__global__ void k_scan(int* __restrict__ counts_all, int* __restrict__ off_all, int* __restrict__ cur_all) {
    const int type = blockIdx.x;
    int* counts = counts_all + type * P_N;
    int* offs   = off_all   + type * P_N;
    int* curs   = cur_all   + type * P_N;
    const int T = 256;
    const int CH = (P_N + T - 1) / T;
    int t = threadIdx.x;
    __shared__ int sums[T];
    __shared__ int pref[T];
    int local = 0;
    int p0 = t * CH;
    for (int i = 0; i < CH; ++i) {
        int p = p0 + i;
        if (p < P_N) local += counts[p];
    }
    sums[t] = local;
    __syncthreads();
    if (t == 0) {
        int run = 0;
        for (int j = 0; j < T; ++j) { pref[j] = run; run += sums[j]; }
    }
    __syncthreads();
    int run = pref[t];
    for (int i = 0; i < CH; ++i) {
        int p = p0 + i;
        if (p < P_N) { offs[p] = run; curs[p] = run; run += counts[p]; }
    }
}

// ---------------- CSR fill ----------------
__global__ void k_fill(const int* __restrict__ idx, int n, int* __restrict__ cur,
                       int* __restrict__ list, int* __restrict__ splan) {
    int i = blockIdx.x * blockDim.x + threadIdx.x;
    int stride = gridDim.x * blockDim.x;
    for (; i < n; i += stride) {
        int p = idx[i];
        int pos = atomicAdd(&cur[p], 1);
        list[pos] = i;
        splan[pos] = p;
    }
}

// ---------------- W prep: WT[n][k] = bf16(W[k][n]) ----------------
__global__ void k_prepw(const float* __restrict__ W, ushort* __restrict__ WT, int D) {
    int i = blockIdx.x * blockDim.x + threadIdx.x;
    if (i >= HD * D) return;
    int n = i / D, k = i - n * D;
    WT[i] = f2bf(W[k * HD + n]);
}

// ---------------- encoder GEMM + fused segment-sum, v4 (pipelined) ----------
// Block owns TPB consecutive 64-row tiles. Wave w computes rows w*16..w*16+15
// x 128 cols per tile. Gathers for tile t+1 issued right after tile t's cvt;
// list/splan prefetch runs 2 tiles ahead. 128-thread column reduce with
// per-block run carry (sorted plan ids).
template<int D, int TPB>
__global__ __launch_bounds__(256, 3) void k_enc(
    const float* __restrict__ feat, const ushort* __restrict__ WT, const float* __restrict__ bias,
    const int* __restrict__ list, const int* __restrict__ splan, int N,
    float* __restrict__ x, int toff, int NT)
{
    constexpr int NKS = D / 32;
    __shared__ float Cs[64][132];
    __shared__ int plans[64];
    const int t = threadIdx.x;
    const int w = t >> 6, lane = t & 63;
    const int lq = lane >> 4, lr = lane & 15;
    const int t0 = blockIdx.x * TPB;
    if (t0 >= NT) return;
    const int Nc = N - 1;
    const int rlocal = w * 16 + lr;

    float bval[8];
    #pragma unroll
    for (int nf = 0; nf < 8; ++nf) bval[nf] = bias[nf * 16 + lr];

    // ---- prologue: tile0 gathers + tile1 prefetch ----
    int m0 = t0 * 64;
    int listv = list[min(m0 + rlocal, Nc)];
    int plansv_cur = -1;
    if (t < 64) plansv_cur = (m0 + t < N) ? splan[m0 + t] : -1;

    float4 st[2 * NKS];
    {
        const float* ap = feat + (size_t)listv * D;
        #pragma unroll
        for (int ks = 0; ks < NKS; ++ks) {
            st[2 * ks]     = *(const float4*)(ap + ks * 32 + lq * 8);
            st[2 * ks + 1] = *(const float4*)(ap + ks * 32 + lq * 8 + 4);
        }
    }
    int m1 = min(t0 + 1, NT - 1) * 64;
    int listv_pf = list[min(m1 + rlocal, Nc)];
    int plansv_pf = -1;
    if (t < 64) plansv_pf = (m1 + t < N) ? splan[m1 + t] : -1;

    // reduce carry state (t < 128 only)
    int curp = -1;
    float srun = 0.f;
    const int col = t & 127;

    const ushort* wp = WT + lr * D + lq * 8;

    for (int tt = 0; tt < TPB; ++tt) {
        const int tile = t0 + tt;
        if (tile >= NT) break;

        // (a) publish this tile's plan ids
        if (t < 64) plans[t] = plansv_cur;

        // (b) convert staged gathers (forces the wait)
        short8v a[NKS];
        #pragma unroll
        for (int ks = 0; ks < NKS; ++ks) a[ks] = cvt8(st[2 * ks], st[2 * ks + 1]);

        // (c) issue gathers for tile+1 (they land during this tile's body)
        {
            const float* apn = feat + (size_t)listv_pf * D;
            #pragma unroll
            for (int ks = 0; ks < NKS; ++ks) {
                st[2 * ks]     = *(const float4*)(apn + ks * 32 + lq * 8);
                st[2 * ks + 1] = *(const float4*)(apn + ks * 32 + lq * 8 + 4);
            }
        }

        // (d) prefetch list/splan for tile+2 (clamped; unused if OOB)
        int m2 = min(tile + 2, NT - 1) * 64;
        int listv_pf2 = list[min(m2 + rlocal, Nc)];
        int plansv_pf2 = -1;
        if (t < 64) plansv_pf2 = (m2 + t < N) ? splan[m2 + t] : -1;

        // (e) MFMA
        float4v acc[8];
        #pragma unroll
        for (int nf = 0; nf < 8; ++nf) acc[nf] = (float4v){0.f, 0.f, 0.f, 0.f};
        #pragma unroll
        for (int ks = 0; ks < NKS; ++ks) {
            #pragma unroll
            for (int nf = 0; nf < 8; ++nf) {
                short8v b = *(const short8v*)(wp + nf * 16 * D + ks * 32);
                acc[nf] = __builtin_amdgcn_mfma_f32_16x16x32_bf16(a[ks], b, acc[nf], 0, 0, 0);
            }
        }

        // (e2) dump bias+ReLU to LDS
        #pragma unroll
        for (int nf = 0; nf < 8; ++nf) {
            const int c = nf * 16 + lr;
            const int rb = w * 16 + lq * 4;
            #pragma unroll
            for (int j = 0; j < 4; ++j)
                Cs[rb + j][c] = fmaxf(acc[nf][j] + bval[nf], 0.f);
        }
        __syncthreads();                       // (f)

        // (g) column reduce with carry (sorted plans; uniform per wave)
        if (t < 128) {
            for (int r = 0; r < 64; ++r) {
                int p = plans[r];
                if (p != curp) {
                    if (curp >= 0) atomicAdd(&x[(size_t)curp * 512 + toff + col], srun);
                    srun = 0.f; curp = p;
                }
                if (p >= 0) srun += Cs[r][col];
            }
        }
        __syncthreads();                       // (h)

        // rotate pipeline registers
        listv_pf = listv_pf2;
        plansv_cur = plansv_pf;
        plansv_pf = plansv_pf2;
    }
    if (t < 128 && curp >= 0)
        atomicAdd(&x[(size_t)curp * 512 + toff + col], srun);
}

// ---------------- 1/count ----------------
__global__ void k_invc(const int* __restrict__ counts_all, float* __restrict__ invc) {
    int i = blockIdx.x * blockDim.x + threadIdx.x;
    if (i < 4 * P_N) invc[i] = 1.f / (float)max(counts_all[i], 1);
}

// ---------------- BN batch stats ----------------
__global__ __launch_bounds__(512) void k_bnstats(const float* __restrict__ x,
                                                 const float* __restrict__ invc,
                                                 float* __restrict__ bnsum) {
    const int t = threadIdx.x;
    const int r0 = blockIdx.x * 79;
    const int r1 = min(r0 + 79, P_N);
    const float* ic = invc + (t >> 7) * P_N;
    float s = 0.f, q = 0.f;
    for (int r = r0; r < r1; ++r) {
        float v = x[(size_t)r * 512 + t] * ic[r];
        s += v; q += v * v;
    }
    atomicAdd(&bnsum[t], s);
    atomicAdd(&bnsum[512 + t], q);
}

__global__ __launch_bounds__(512) void k_bnfinal(const float* __restrict__ bnsum,
                                                 const float* __restrict__ gamma, const float* __restrict__ beta,
                                                 float* __restrict__ scale, float* __restrict__ shiftv) {
    const int t = threadIdx.x;
    const float invn = 1.f / (float)P_N;
    float mu  = bnsum[t] * invn;
    float var = bnsum[512 + t] * invn - mu * mu;
    float rstd = rsqrtf(fmaxf(var, 0.f) + 1e-5f);
    float sc = gamma[t] * rstd;
    scale[t]  = sc;
    shiftv[t] = beta[t] - mu * sc;
}

// ---------------- fused MFMA head: BN + 512->128->128->1, 64 plans/block ----
__global__ __launch_bounds__(256) void k_head(
    const float* __restrict__ x, const float* __restrict__ invc,
    const float* __restrict__ scale, const float* __restrict__ shiftv,
    const ushort* __restrict__ WT1, const float* __restrict__ b1,
    const ushort* __restrict__ WT2, const float* __restrict__ b2,
    const float* __restrict__ W3, const float* __restrict__ b3,
    float* __restrict__ out)
{
    __shared__ float h[4][16][132];
    const int t = threadIdx.x;
    const int w = t >> 6, lane = t & 63;
    const int lq = lane >> 4, lr = lane & 15;
    const int p0 = blockIdx.x * 64;
    const int row = p0 + w * 16 + lr;
    const int rowc = min(row, P_N - 1);
    const float* xr = x + (size_t)rowc * 512;

    float4v acc[8];
    #pragma unroll
    for (int nf = 0; nf < 8; ++nf) acc[nf] = (float4v){0.f, 0.f, 0.f, 0.f};

    #pragma unroll
    for (int kc = 0; kc < 4; ++kc) {
        const float ic = invc[kc * P_N + rowc];
        float4 st[8];
        #pragma unroll
        for (int k2 = 0; k2 < 4; ++k2) {
            const int k0 = kc * 128 + k2 * 32 + lq * 8;
            st[2 * k2]     = *(const float4*)(xr + k0);
            st[2 * k2 + 1] = *(const float4*)(xr + k0 + 4);
        }
        short8v a[4];
        #pragma unroll
        for (int k2 = 0; k2 < 4; ++k2) {
            const int k0 = kc * 128 + k2 * 32 + lq * 8;
            float4 sc0 = *(const float4*)(scale + k0);
            float4 sc1 = *(const float4*)(scale + k0 + 4);
            float4 sh0 = *(const float4*)(shiftv + k0);
            float4 sh1 = *(const float4*)(shiftv + k0 + 4);
            float4 v0, v1;
            v0.x = st[2*k2].x   * ic * sc0.x + sh0.x;
            v0.y = st[2*k2].y   * ic * sc0.y + sh0.y;
            v0.z = st[2*k2].z   * ic * sc0.z + sh0.z;
            v0.w = st[2*k2].w   * ic * sc0.w + sh0.w;
            v1.x = st[2*k2+1].x * ic * sc1.x + sh1.x;
            v1.y = st[2*k2+1].y * ic * sc1.y + sh1.y;
            v1.z = st[2*k2+1].z * ic * sc1.z + sh1.z;
            v1.w = st[2*k2+1].w * ic * sc1.w + sh1.w;
            a[k2] = cvt8(v0, v1);
        }
        #pragma unroll
        for (int k2 = 0; k2 < 4; ++k2) {
            const int ks = kc * 4 + k2;
            #pragma unroll
            for (int nf = 0; nf < 8; ++nf) {
                short8v b = *(const short8v*)(WT1 + (nf * 16 + lr) * 512 + ks * 32 + lq * 8);
                acc[nf] = __builtin_amdgcn_mfma_f32_16x16x32_bf16(a[k2], b, acc[nf], 0, 0, 0);
            }
        }
    }
    #pragma unroll
    for (int nf = 0; nf < 8; ++nf) {
        const float bv = b1[nf * 16 + lr];
        #pragma unroll
        for (int j = 0; j < 4; ++j)
            h[w][lq * 4 + j][nf * 16 + lr] = fmaxf(acc[nf][j] + bv, 0.f);
    }
    __syncthreads();

    float4v acc2[8];
    #pragma unroll
    for (int nf = 0; nf < 8; ++nf) acc2[nf] = (float4v){0.f, 0.f, 0.f, 0.f};
    short8v a2[4];
    #pragma unroll
    for (int ks = 0; ks < 4; ++ks) {
        const float* hp = &h[w][lr][ks * 32 + lq * 8];
        float4 h0 = *(const float4*)hp;
        float4 h1v = *(const float4*)(hp + 4);
        a2[ks] = cvt8(h0, h1v);
    }
    #pragma unroll
    for (int ks = 0; ks < 4; ++ks) {
        #pragma unroll
        for (int nf = 0; nf < 8; ++nf) {
            short8v b = *(const short8v*)(WT2 + (nf * 16 + lr) * 128 + ks * 32 + lq * 8);
            acc2[nf] = __builtin_amdgcn_mfma_f32_16x16x32_bf16(a2[ks], b, acc2[nf], 0, 0, 0);
        }
    }

    float s0 = 0.f, s1 = 0.f, s2 = 0.f, s3 = 0.f;
    #pragma unroll
    for (int nf = 0; nf < 8; ++nf) {
        const int c = nf * 16 + lr;
        const float w3v = W3[c];
        const float bv = b2[c];
        s0 += fmaxf(acc2[nf][0] + bv, 0.f) * w3v;
        s1 += fmaxf(acc2[nf][1] + bv, 0.f) * w3v;
        s2 += fmaxf(acc2[nf][2] + bv, 0.f) * w3v;
        s3 += fmaxf(acc2[nf][3] + bv, 0.f) * w3v;
    }
    #pragma unroll
    for (int o = 1; o < 16; o <<= 1) {
        s0 += __shfl_xor(s0, o);
        s1 += __shfl_xor(s1, o);
        s2 += __shfl_xor(s2, o);
        s3 += __shfl_xor(s3, o);
    }
    if (lr == 0) {
        const int rb = p0 + w * 16 + lq * 4;
        const float bb = b3[0];
        if (rb + 0 < P_N) out[rb + 0] = s0 + bb;
        if (rb + 1 < P_N) out[rb + 1] = s1 + bb;
        if (rb + 2 < P_N) out[rb + 2] = s2 + bb;
        if (rb + 3 < P_N) out[rb + 3] = s3 + bb;
    }
}

extern "C" void kernel_launch(void* const* d_in, const int* in_sizes, int n_in,
                              void* d_out, int out_size, void* d_ws, size_t ws_size,
                              hipStream_t stream)
{
    const float* feats[4] = {(const float*)d_in[0], (const float*)d_in[4], (const float*)d_in[8],  (const float*)d_in[12]};
    const int*   idxs[4]  = {(const int*)d_in[1],   (const int*)d_in[5],   (const int*)d_in[9],   (const int*)d_in[13]};
    const float* Ws[4]    = {(const float*)d_in[2], (const float*)d_in[6], (const float*)d_in[10], (const float*)d_in[14]};
    const float* bs[4]    = {(const float*)d_in[3], (const float*)d_in[7], (const float*)d_in[11], (const float*)d_in[15]};
    const float* gamma = (const float*)d_in[16];
    const float* beta  = (const float*)d_in[17];
    const float* W1 = (const float*)d_in[18]; const float* b1 = (const float*)d_in[19];
    const float* W2 = (const float*)d_in[20]; const float* b2 = (const float*)d_in[21];
    const float* W3 = (const float*)d_in[22]; const float* b3 = (const float*)d_in[23];
    int Ns[4] = {in_sizes[1], in_sizes[5], in_sizes[9], in_sizes[13]};
    const int Ds[4] = {96, 160, 64, 64};

    // ws layout (bytes)
    char* ws = (char*)d_ws;
    int* counts = (int*)(ws + 0);
    int* offs   = (int*)(ws + 320000);
    int* curs   = (int*)(ws + 640000);       // dead after k_fill -> WT1/WT2 overlay
    int* lists[4];
    lists[0] = (int*)(ws + 960000);
    lists[1] = (int*)(ws + 1360000);
    lists[2] = (int*)(ws + 2960000);
    lists[3] = (int*)(ws + 3200000);
    int* splans[4];
    splans[0] = (int*)(ws + 3520000);
    splans[1] = (int*)(ws + 3920000);
    splans[2] = (int*)(ws + 5520000);
    splans[3] = (int*)(ws + 5760000);
    ushort* WTs[4];
    WTs[0] = (ushort*)(ws + 6080000);
    WTs[1] = (ushort*)(ws + 6104576);
    WTs[2] = (ushort*)(ws + 6145536);
    WTs[3] = (ushort*)(ws + 6161920);
    float* invc   = (float*)(ws + 6178304);
    float* x      = (float*)(ws + 6498304);
    float* bnsum  = (float*)(ws + 47458304);
    float* scale  = (float*)(ws + 47462400);
    float* shiftv = (float*)(ws + 47464448);
    ushort* WT1   = (ushort*)(ws + 640000);
    ushort* WT2   = (ushort*)(ws + 771072);

    hipMemsetAsync(counts, 0, 4 * P_N * sizeof(int), stream);
    hipMemsetAsync(bnsum, 0, 1024 * sizeof(float), stream);
    hipMemsetAsync(x, 0, (size_t)P_N * 512 * sizeof(float), stream);

    for (int tp = 0; tp < 4; ++tp) {
        int gb = (Ns[tp] + 255) / 256; if (gb > 2048) gb = 2048;
        k_count<<<gb, 256, 0, stream>>>(idxs[tp], Ns[tp], counts + tp * P_N);
    }
    k_scan<<<4, 256, 0, stream>>>(counts, offs, curs);
    for (int tp = 0; tp < 4; ++tp) {
        int gb = (Ns[tp] + 255) / 256; if (gb > 2048) gb = 2048;
        k_fill<<<gb, 256, 0, stream>>>(idxs[tp], Ns[tp], curs + tp * P_N, lists[tp], splans[tp]);
        k_prepw<<<(HD * Ds[tp] + 255) / 256, 256, 0, stream>>>(Ws[tp], WTs[tp], Ds[tp]);
    }
    k_prepw<<<(HD * 512 + 255) / 256, 256, 0, stream>>>(W1, WT1, 512);
    k_prepw<<<(HD * 128 + 255) / 256, 256, 0, stream>>>(W2, WT2, 128);

    // encoder: NT tiles of 64 rows; TPB tiles per block
    {
        int NT0 = (Ns[0] + 63) / 64;   // table, TPB=4
        int NT1 = (Ns[1] + 63) / 64;   // pred,  TPB=8
        int NT2 = (Ns[2] + 63) / 64;   // agg,   TPB=4
        int NT3 = (Ns[3] + 63) / 64;   // join,  TPB=4
        k_enc< 96, 4><<<(NT0 + 3) / 4, 256, 0, stream>>>(feats[0], WTs[0], bs[0], lists[0], splans[0], Ns[0], x, 0,   NT0);
        k_enc<160, 8><<<(NT1 + 7) / 8, 256, 0, stream>>>(feats[1], WTs[1], bs[1], lists[1], splans[1], Ns[1], x, 128, NT1);
        k_enc< 64, 4><<<(NT2 + 3) / 4, 256, 0, stream>>>(feats[2], WTs[2], bs[2], lists[2], splans[2], Ns[2], x, 256, NT2);
        k_enc< 64, 4><<<(NT3 + 3) / 4, 256, 0, stream>>>(feats[3], WTs[3], bs[3], lists[3], splans[3], Ns[3], x, 384, NT3);
    }

    k_invc<<<(4 * P_N + 255) / 256, 256, 0, stream>>>(counts, invc);
    k_bnstats<<<256, 512, 0, stream>>>(x, invc, bnsum);
    k_bnfinal<<<1, 512, 0, stream>>>(bnsum, gamma, beta, scale, shiftv);
    k_head<<<(P_N + 63) / 64, 256, 0, stream>>>(x, invc, scale, shiftv,
                                                WT1, b1, WT2, b2, W3, b3, (float*)d_out);
}

// Round 5
// 492.225 us; speedup vs baseline: 1.3850x; 1.3850x over previous
//
#include <hip/hip_runtime.h>
#include <cstdint>

// MSCN forward, round 5:
//  k_enc v5: 8-wave col-split GEMM. B (weights) in registers loaded once per
//  block; A (gathered feat rows) DMA'd via global_load_lds into double-buffered
//  odd-stride LDS (conflict-free ds_read_b128); fused carry segment-sum.
//  Per-tile loop touches only LDS + registers + HBM stream.

constexpr int P_N = 20000;
constexpr int HD  = 128;

typedef __attribute__((ext_vector_type(8))) short  short8v;
typedef __attribute__((ext_vector_type(4))) float  float4v;
typedef __attribute__((ext_vector_type(8))) float  float8v;
typedef __attribute__((ext_vector_type(8))) __bf16 bf16x8;

__device__ inline ushort f2bf(float f) {                       // RNE f32->bf16
    uint32_t u = __builtin_bit_cast(uint32_t, f);
    u += 0x7fffu + ((u >> 16) & 1u);
    return (ushort)(u >> 16);
}
__device__ inline short8v cvt8(float4 x0, float4 x1) {         // bit-trick (head)
    short8v v;
    v[0] = (short)f2bf(x0.x); v[1] = (short)f2bf(x0.y);
    v[2] = (short)f2bf(x0.z); v[3] = (short)f2bf(x0.w);
    v[4] = (short)f2bf(x1.x); v[5] = (short)f2bf(x1.y);
    v[6] = (short)f2bf(x1.z); v[7] = (short)f2bf(x1.w);
    return v;
}
__device__ inline short8v cvt8v(float4 a, float4 b) {          // v_cvt_pk path (enc)
    float8v f = {a.x, a.y, a.z, a.w, b.x, b.y, b.z, b.w};
    bf16x8 h = __builtin_convertvector(f, bf16x8);
    return __builtin_bit_cast(short8v, h);
}

typedef __attribute__((address_space(3))) char as3char;
__device__ inline void gld16(const void* g, as3char* l) {
    __builtin_amdgcn_global_load_lds(
        (const __attribute__((address_space(1))) void*)g,
        (__attribute__((address_space(3))) void*)l, 16, 0, 0);
}

// ---------------- histogram ----------------
__global__ void k_count(const int* __restrict__ idx, int n, int* __restrict__ counts) {
    int i = blockIdx.x * blockDim.x + threadIdx.x;
    int stride = gridDim.x * blockDim.x;
    for (; i < n; i += stride) atomicAdd(&counts[idx[i]], 1);
}

// ---------------- exclusive scan, one block per type ----------------
__global__ void k_scan(int* __restrict__ counts_all, int* __restrict__ off_all, int* __restrict__ cur_all) {
    const int type = blockIdx.x;
    int* counts = counts_all + type * P_N;
    int* offs   = off_all   + type * P_N;
    int* curs   = cur_all   + type * P_N;
    const int T = 256;
    const int CH = (P_N + T - 1) / T;
    int t = threadIdx.x;
    __shared__ int sums[T];
    __shared__ int pref[T];
    int local = 0;
    int p0 = t * CH;
    for (int i = 0; i < CH; ++i) {
        int p = p0 + i;
        if (p < P_N) local += counts[p];
    }
    sums[t] = local;
    __syncthreads();
    if (t == 0) {
        int run = 0;
        for (int j = 0; j < T; ++j) { pref[j] = run; run += sums[j]; }
    }
    __syncthreads();
    int run = pref[t];
    for (int i = 0; i < CH; ++i) {
        int p = p0 + i;
        if (p < P_N) { offs[p] = run; curs[p] = run; run += counts[p]; }
    }
}

// ---------------- CSR fill ----------------
__global__ void k_fill(const int* __restrict__ idx, int n, int* __restrict__ cur,
                       int* __restrict__ list, int* __restrict__ splan) {
    int i = blockIdx.x * blockDim.x + threadIdx.x;
    int stride = gridDim.x * blockDim.x;
    for (; i < n; i += stride) {
        int p = idx[i];
        int pos = atomicAdd(&cur[p], 1);
        list[pos] = i;
        splan[pos] = p;
    }
}

// ---------------- W prep: WT[n][k] = bf16(W[k][n]) ----------------
__global__ void k_prepw(const float* __restrict__ W, ushort* __restrict__ WT, int D) {
    int i = blockIdx.x * blockDim.x + threadIdx.x;
    if (i >= HD * D) return;
    int n = i / D, k = i - n * D;
    WT[i] = f2bf(W[k * HD + n]);
}

// ---------------- encoder GEMM + fused segment-sum, v5 ----------------
// 512 thr = 8 waves. Wave w owns cols [w*16, w*16+16). B in regs (once/block).
// A: 32-row tiles DMA'd to LDS (odd 16B stride A16), double-buffered.
// list/splan must be padded (64 entries: list=0, splan=-1).
template<int D>
__global__ __launch_bounds__(512, 4) void k_enc(
    const float* __restrict__ feat, const ushort* __restrict__ WT, const float* __restrict__ bias,
    const int* __restrict__ list, const int* __restrict__ splan, int N,
    float* __restrict__ x, int toff, int NT, int TPB)
{
    constexpr int NKS = D / 32;
    constexpr int CH  = D / 8;              // 16B data chunks per row
    constexpr int A16 = 2 * CH + 1;         // padded 16B units per row (odd)
    constexpr int TI  = (32 * A16 + 63) / 64;   // DMA instrs per tile
    constexpr int LO = TI / 8, REM = TI % 8;

    __shared__ __align__(16) float Abuf0[TI * 256];
    __shared__ __align__(16) float Abuf1[TI * 256];
    __shared__ float Cs[32][132];
    __shared__ int plbuf[3][32];

    const int t = threadIdx.x;
    const int w = t >> 6, lane = t & 63;
    const int lq = lane >> 4, lr = lane & 15;
    const int t0 = blockIdx.x * TPB;
    if (t0 >= NT) return;
    const int my_nt = min(TPB, NT - t0);
    const char* fbase = (const char*)feat;
    constexpr size_t DB = (size_t)D * 4;

    // per-wave DMA share: instr ii = w + 8*j, j < cw
    const int cw = LO + (w < REM);
    int rowi[3], soff[3];
    #pragma unroll
    for (int j = 0; j < 3; ++j) {
        int ii = w + 8 * j;
        int s = ii * 64 + lane;
        int r = s / A16;
        int kc2 = s - r * A16;
        kc2 = min(kc2, 2 * CH - 1);
        rowi[j] = min(r, 31);
        soff[j] = kc2 * 16;
    }

    // B fragments + bias (resident for whole block)
    short8v b[NKS];
    #pragma unroll
    for (int ks = 0; ks < NKS; ++ks)
        b[ks] = *(const short8v*)(WT + (w * 16 + lr) * D + ks * 32 + lq * 8);
    const float bval = bias[w * 16 + lr];

    as3char* ab0 = (as3char*)(char*)Abuf0;
    as3char* ab1 = (as3char*)(char*)Abuf1;

    // ---- prologue: lv(tile0) -> stage(tile0) -> plans(0) -> lv(tile1) ----
    int lv[3];
    {
        const int m0 = t0 * 32;
        #pragma unroll
        for (int j = 0; j < 3; ++j) if (j < cw) lv[j] = list[m0 + rowi[j]];
        #pragma unroll
        for (int j = 0; j < 3; ++j) if (j < cw)
            gld16(fbase + (size_t)lv[j] * DB + soff[j], ab0 + (w + 8 * j) * 1024);
        if (t < 32) plbuf[0][t] = splan[m0 + t];
        const int mA = min(t0 + 1, NT - 1) * 32;
        #pragma unroll
        for (int j = 0; j < 3; ++j) if (j < cw) lv[j] = list[mA + rowi[j]];
    }

    int curp = -1;
    float srun = 0.f;

    for (int tt = 0; tt < my_nt; ++tt) {
        const int cur = tt & 1;
        // ---- stage tile tt+1 (clamped) ----
        as3char* dst = cur ? ab0 : ab1;
        #pragma unroll
        for (int j = 0; j < 3; ++j) if (j < cw)
            gld16(fbase + (size_t)lv[j] * DB + soff[j], dst + (w + 8 * j) * 1024);
        // plans for tile tt+1 (triple buffer: tile q -> plbuf[q%3])
        if (t < 32) {
            int pv = splan[min(t0 + tt + 1, NT - 1) * 32 + t];
            plbuf[(tt + 1) % 3][t] = pv;
        }
        // lv for tile tt+2 (WAR-safe: reloads after DMA consumed addresses)
        {
            const int mn2 = min(t0 + tt + 2, NT - 1) * 32;
            #pragma unroll
            for (int j = 0; j < 3; ++j) if (j < cw) lv[j] = list[mn2 + rowi[j]];
        }
        __syncthreads();   // drains DMA: buf[cur] (and buf[cur^1]) resident

        // ---- compute tile tt from buf[cur] ----
        {
            const float* Ab = cur ? Abuf1 : Abuf0;
            const float* a0b = Ab + ((size_t)(lr * A16 + lq * 2)) * 4;
            const float* a1b = Ab + ((size_t)((16 + lr) * A16 + lq * 2)) * 4;
            float4v acc0 = {0.f, 0.f, 0.f, 0.f};
            float4v acc1 = {0.f, 0.f, 0.f, 0.f};
            #pragma unroll
            for (int ks = 0; ks < NKS; ++ks) {
                float4 x0 = *(const float4*)(a0b + ks * 32);
                float4 x1 = *(const float4*)(a0b + ks * 32 + 4);
                acc0 = __builtin_amdgcn_mfma_f32_16x16x32_bf16(cvt8v(x0, x1), b[ks], acc0, 0, 0, 0);
                float4 y0 = *(const float4*)(a1b + ks * 32);
                float4 y1 = *(const float4*)(a1b + ks * 32 + 4);
                acc1 = __builtin_amdgcn_mfma_f32_16x16x32_bf16(cvt8v(y0, y1), b[ks], acc1, 0, 0, 0);
            }
            #pragma unroll
            for (int j = 0; j < 4; ++j) {
                Cs[lq * 4 + j][w * 16 + lr]      = fmaxf(acc0[j] + bval, 0.f);
                Cs[16 + lq * 4 + j][w * 16 + lr] = fmaxf(acc1[j] + bval, 0.f);
            }
        }
        __syncthreads();   // Cs complete

        // ---- segment scan with carry (t<128: col t) ----
        if (t < 128) {
            const int pq = tt % 3;
            for (int r = 0; r < 32; ++r) {
                int p = plbuf[pq][r];
                if (p != curp) {
                    if (curp >= 0) atomicAdd(&x[(size_t)curp * 512 + toff + t], srun);
                    srun = 0.f; curp = p;
                }
                if (p >= 0) srun += Cs[r][t];
            }
        }
        // next iteration's first __syncthreads protects Cs/plbuf reuse
    }
    if (t < 128 && curp >= 0)
        atomicAdd(&x[(size_t)curp * 512 + toff + t], srun);
}

// ---------------- 1/count ----------------
__global__ void k_invc(const int* __restrict__ counts_all, float* __restrict__ invc) {
    int i = blockIdx.x * blockDim.x + threadIdx.x;
    if (i < 4 * P_N) invc[i] = 1.f / (float)max(counts_all[i], 1);
}

// ---------------- BN batch stats ----------------
__global__ __launch_bounds__(512) void k_bnstats(const float* __restrict__ x,
                                                 const float* __restrict__ invc,
                                                 float* __restrict__ bnsum) {
    const int t = threadIdx.x;
    const int r0 = blockIdx.x * 79;
    const int r1 = min(r0 + 79, P_N);
    const float* ic = invc + (t >> 7) * P_N;
    float s = 0.f, q = 0.f;
    for (int r = r0; r < r1; ++r) {
        float v = x[(size_t)r * 512 + t] * ic[r];
        s += v; q += v * v;
    }
    atomicAdd(&bnsum[t], s);
    atomicAdd(&bnsum[512 + t], q);
}

__global__ __launch_bounds__(512) void k_bnfinal(const float* __restrict__ bnsum,
                                                 const float* __restrict__ gamma, const float* __restrict__ beta,
                                                 float* __restrict__ scale, float* __restrict__ shiftv) {
    const int t = threadIdx.x;
    const float invn = 1.f / (float)P_N;
    float mu  = bnsum[t] * invn;
    float var = bnsum[512 + t] * invn - mu * mu;
    float rstd = rsqrtf(fmaxf(var, 0.f) + 1e-5f);
    float sc = gamma[t] * rstd;
    scale[t]  = sc;
    shiftv[t] = beta[t] - mu * sc;
}

// ---------------- fused MFMA head: BN + 512->128->128->1, 64 plans/block ----
__global__ __launch_bounds__(256) void k_head(
    const float* __restrict__ x, const float* __restrict__ invc,
    const float* __restrict__ scale, const float* __restrict__ shiftv,
    const ushort* __restrict__ WT1, const float* __restrict__ b1,
    const ushort* __restrict__ WT2, const float* __restrict__ b2,
    const float* __restrict__ W3, const float* __restrict__ b3,
    float* __restrict__ out)
{
    __shared__ float h[4][16][132];
    const int t = threadIdx.x;
    const int w = t >> 6, lane = t & 63;
    const int lq = lane >> 4, lr = lane & 15;
    const int p0 = blockIdx.x * 64;
    const int row = p0 + w * 16 + lr;
    const int rowc = min(row, P_N - 1);
    const float* xr = x + (size_t)rowc * 512;

    float4v acc[8];
    #pragma unroll
    for (int nf = 0; nf < 8; ++nf) acc[nf] = (float4v){0.f, 0.f, 0.f, 0.f};

    #pragma unroll
    for (int kc = 0; kc < 4; ++kc) {
        const float ic = invc[kc * P_N + rowc];
        float4 st[8];
        #pragma unroll
        for (int k2 = 0; k2 < 4; ++k2) {
            const int k0 = kc * 128 + k2 * 32 + lq * 8;
            st[2 * k2]     = *(const float4*)(xr + k0);
            st[2 * k2 + 1] = *(const float4*)(xr + k0 + 4);
        }
        short8v a[4];
        #pragma unroll
        for (int k2 = 0; k2 < 4; ++k2) {
            const int k0 = kc * 128 + k2 * 32 + lq * 8;
            float4 sc0 = *(const float4*)(scale + k0);
            float4 sc1 = *(const float4*)(scale + k0 + 4);
            float4 sh0 = *(const float4*)(shiftv + k0);
            float4 sh1 = *(const float4*)(shiftv + k0 + 4);
            float4 v0, v1;
            v0.x = st[2*k2].x   * ic * sc0.x + sh0.x;
            v0.y = st[2*k2].y   * ic * sc0.y + sh0.y;
            v0.z = st[2*k2].z   * ic * sc0.z + sh0.z;
            v0.w = st[2*k2].w   * ic * sc0.w + sh0.w;
            v1.x = st[2*k2+1].x * ic * sc1.x + sh1.x;
            v1.y = st[2*k2+1].y * ic * sc1.y + sh1.y;
            v1.z = st[2*k2+1].z * ic * sc1.z + sh1.z;
            v1.w = st[2*k2+1].w * ic * sc1.w + sh1.w;
            a[k2] = cvt8(v0, v1);
        }
        #pragma unroll
        for (int k2 = 0; k2 < 4; ++k2) {
            const int ks = kc * 4 + k2;
            #pragma unroll
            for (int nf = 0; nf < 8; ++nf) {
                short8v b = *(const short8v*)(WT1 + (nf * 16 + lr) * 512 + ks * 32 + lq * 8);
                acc[nf] = __builtin_amdgcn_mfma_f32_16x16x32_bf16(a[k2], b, acc[nf], 0, 0, 0);
            }
        }
    }
    #pragma unroll
    for (int nf = 0; nf < 8; ++nf) {
        const float bv = b1[nf * 16 + lr];
        #pragma unroll
        for (int j = 0; j < 4; ++j)
            h[w][lq * 4 + j][nf * 16 + lr] = fmaxf(acc[nf][j] + bv, 0.f);
    }
    __syncthreads();

    float4v acc2[8];
    #pragma unroll
    for (int nf = 0; nf < 8; ++nf) acc2[nf] = (float4v){0.f, 0.f, 0.f, 0.f};
    short8v a2[4];
    #pragma unroll
    for (int ks = 0; ks < 4; ++ks) {
        const float* hp = &h[w][lr][ks * 32 + lq * 8];
        float4 h0 = *(const float4*)hp;
        float4 h1v = *(const float4*)(hp + 4);
        a2[ks] = cvt8(h0, h1v);
    }
    #pragma unroll
    for (int ks = 0; ks < 4; ++ks) {
        #pragma unroll
        for (int nf = 0; nf < 8; ++nf) {
            short8v b = *(const short8v*)(WT2 + (nf * 16 + lr) * 128 + ks * 32 + lq * 8);
            acc2[nf] = __builtin_amdgcn_mfma_f32_16x16x32_bf16(a2[ks], b, acc2[nf], 0, 0, 0);
        }
    }

    float s0 = 0.f, s1 = 0.f, s2 = 0.f, s3 = 0.f;
    #pragma unroll
    for (int nf = 0; nf < 8; ++nf) {
        const int c = nf * 16 + lr;
        const float w3v = W3[c];
        const float bv = b2[c];
        s0 += fmaxf(acc2[nf][0] + bv, 0.f) * w3v;
        s1 += fmaxf(acc2[nf][1] + bv, 0.f) * w3v;
        s2 += fmaxf(acc2[nf][2] + bv, 0.f) * w3v;
        s3 += fmaxf(acc2[nf][3] + bv, 0.f) * w3v;
    }
    #pragma unroll
    for (int o = 1; o < 16; o <<= 1) {
        s0 += __shfl_xor(s0, o);
        s1 += __shfl_xor(s1, o);
        s2 += __shfl_xor(s2, o);
        s3 += __shfl_xor(s3, o);
    }
    if (lr == 0) {
        const int rb = p0 + w * 16 + lq * 4;
        const float bb = b3[0];
        if (rb + 0 < P_N) out[rb + 0] = s0 + bb;
        if (rb + 1 < P_N) out[rb + 1] = s1 + bb;
        if (rb + 2 < P_N) out[rb + 2] = s2 + bb;
        if (rb + 3 < P_N) out[rb + 3] = s3 + bb;
    }
}

extern "C" void kernel_launch(void* const* d_in, const int* in_sizes, int n_in,
                              void* d_out, int out_size, void* d_ws, size_t ws_size,
                              hipStream_t stream)
{
    const float* feats[4] = {(const float*)d_in[0], (const float*)d_in[4], (const float*)d_in[8],  (const float*)d_in[12]};
    const int*   idxs[4]  = {(const int*)d_in[1],   (const int*)d_in[5],   (const int*)d_in[9],   (const int*)d_in[13]};
    const float* Ws[4]    = {(const float*)d_in[2], (const float*)d_in[6], (const float*)d_in[10], (const float*)d_in[14]};
    const float* bs[4]    = {(const float*)d_in[3], (const float*)d_in[7], (const float*)d_in[11], (const float*)d_in[15]};
    const float* gamma = (const float*)d_in[16];
    const float* beta  = (const float*)d_in[17];
    const float* W1 = (const float*)d_in[18]; const float* b1 = (const float*)d_in[19];
    const float* W2 = (const float*)d_in[20]; const float* b2 = (const float*)d_in[21];
    const float* W3 = (const float*)d_in[22]; const float* b3 = (const float*)d_in[23];
    int Ns[4] = {in_sizes[1], in_sizes[5], in_sizes[9], in_sizes[13]};
    const int Ds[4] = {96, 160, 64, 64};

    // ws layout (bytes); lists/splans have +64-entry pads
    char* ws = (char*)d_ws;
    int* counts = (int*)(ws + 0);
    int* offs   = (int*)(ws + 320000);
    int* curs   = (int*)(ws + 640000);       // dead after fill -> WT1/WT2 overlay
    int* lists[4];
    lists[0] = (int*)(ws + 960000);
    lists[1] = (int*)(ws + 1360256);
    lists[2] = (int*)(ws + 2960512);
    lists[3] = (int*)(ws + 3200768);
    int* splans[4];
    splans[0] = (int*)(ws + 3521024);
    splans[1] = (int*)(ws + 3921280);
    splans[2] = (int*)(ws + 5521536);
    splans[3] = (int*)(ws + 5761792);
    ushort* WTs[4];
    WTs[0] = (ushort*)(ws + 6082048);
    WTs[1] = (ushort*)(ws + 6106624);
    WTs[2] = (ushort*)(ws + 6147584);
    WTs[3] = (ushort*)(ws + 6163968);
    float* invc   = (float*)(ws + 6180352);
    float* x      = (float*)(ws + 6500352);   // P*512 f32 = 40.96 MB
    float* bnsum  = (float*)(ws + 47460352);
    float* scale  = (float*)(ws + 47464448);
    float* shiftv = (float*)(ws + 47466496);
    ushort* WT1   = (ushort*)(ws + 640000);
    ushort* WT2   = (ushort*)(ws + 771072);

    hipMemsetAsync(counts, 0, 4 * P_N * sizeof(int), stream);
    hipMemsetAsync(bnsum, 0, 1024 * sizeof(float), stream);
    hipMemsetAsync(x, 0, (size_t)P_N * 512 * sizeof(float), stream);
    for (int tp = 0; tp < 4; ++tp) {   // pads: list=0 (safe row), splan=-1
        hipMemsetAsync((char*)lists[tp]  + (size_t)Ns[tp] * 4, 0x00, 256, stream);
        hipMemsetAsync((char*)splans[tp] + (size_t)Ns[tp] * 4, 0xFF, 256, stream);
    }

    for (int tp = 0; tp < 4; ++tp) {
        int gb = (Ns[tp] + 255) / 256; if (gb > 2048) gb = 2048;
        k_count<<<gb, 256, 0, stream>>>(idxs[tp], Ns[tp], counts + tp * P_N);
    }
    k_scan<<<4, 256, 0, stream>>>(counts, offs, curs);
    for (int tp = 0; tp < 4; ++tp) {
        int gb = (Ns[tp] + 255) / 256; if (gb > 2048) gb = 2048;
        k_fill<<<gb, 256, 0, stream>>>(idxs[tp], Ns[tp], curs + tp * P_N, lists[tp], splans[tp]);
        k_prepw<<<(HD * Ds[tp] + 255) / 256, 256, 0, stream>>>(Ws[tp], WTs[tp], Ds[tp]);
    }
    k_prepw<<<(HD * 512 + 255) / 256, 256, 0, stream>>>(W1, WT1, 512);
    k_prepw<<<(HD * 128 + 255) / 256, 256, 0, stream>>>(W2, WT2, 128);

    // encoders: 32-row tiles, <=512 persistent blocks
    {
        auto cfg = [](int N, int& NT, int& NB, int& TPB) {
            NT = (N + 31) / 32; NB = NT < 512 ? NT : 512; TPB = (NT + NB - 1) / NB;
        };
        int NT, NB, TPB;
        cfg(Ns[0], NT, NB, TPB);
        k_enc< 96><<<NB, 512, 0, stream>>>(feats[0], WTs[0], bs[0], lists[0], splans[0], Ns[0], x, 0,   NT, TPB);
        cfg(Ns[1], NT, NB, TPB);
        k_enc<160><<<NB, 512, 0, stream>>>(feats[1], WTs[1], bs[1], lists[1], splans[1], Ns[1], x, 128, NT, TPB);
        cfg(Ns[2], NT, NB, TPB);
        k_enc< 64><<<NB, 512, 0, stream>>>(feats[2], WTs[2], bs[2], lists[2], splans[2], Ns[2], x, 256, NT, TPB);
        cfg(Ns[3], NT, NB, TPB);
        k_enc< 64><<<NB, 512, 0, stream>>>(feats[3], WTs[3], bs[3], lists[3], splans[3], Ns[3], x, 384, NT, TPB);
    }

    k_invc<<<(4 * P_N + 255) / 256, 256, 0, stream>>>(counts, invc);
    k_bnstats<<<256, 512, 0, stream>>>(x, invc, bnsum);
    k_bnfinal<<<1, 512, 0, stream>>>(bnsum, gamma, beta, scale, shiftv);
    k_head<<<(P_N + 63) / 64, 256, 0, stream>>>(x, invc, scale, shiftv,
                                                WT1, b1, WT2, b2, W3, b3, (float*)d_out);
}